// Round 1
// baseline (325.064 us; speedup 1.0000x reference)
//
#include <hip/hip_runtime.h>
#include <hip/hip_bf16.h>
#include <cstdint>

#define MDIM 32768
#define NDIM 1024
#define KDIM 1024

typedef float          f32x4 __attribute__((ext_vector_type(4)));
typedef short          s16x8 __attribute__((ext_vector_type(8)));
typedef unsigned short u16x8 __attribute__((ext_vector_type(8)));

typedef __attribute__((address_space(1))) unsigned int gu32;
typedef __attribute__((address_space(3))) unsigned int lu32;

// fp32 -> bf16 round-to-nearest-even (inputs are finite; no NaN handling needed)
__device__ __forceinline__ unsigned short f2bf(float f) {
  unsigned int u = __builtin_bit_cast(unsigned int, f);
  u += 0x7fffu + ((u >> 16) & 1u);
  return (unsigned short)(u >> 16);
}

// async global->LDS, 16 bytes per lane (global_load_lds_dwordx4).
// LDS dest is wave-uniform base + lane*16; callers pass lane-linear addresses.
__device__ __forceinline__ void async16(const void* g, void* l) {
  __builtin_amdgcn_global_load_lds((gu32*)g, (lu32*)l, 16, 0, 0);
}

// Pass 1: x (fp32 [M,K]) -> bf16, and (w*mask) (fp32 [N,K]) -> bf16.
__global__ __launch_bounds__(256) void convert_kernel(
    const float* __restrict__ x, const float* __restrict__ w,
    const float* __restrict__ msk,
    unsigned short* __restrict__ xb, unsigned short* __restrict__ wb) {
  const long long i = (long long)blockIdx.x * 256 + threadIdx.x;  // 8-elem group
  const long long nx8 = (long long)MDIM * KDIM / 8;
  const long long nw8 = (long long)NDIM * KDIM / 8;
  if (i < nx8) {
    f32x4 a = ((const f32x4*)x)[2 * i];
    f32x4 b = ((const f32x4*)x)[2 * i + 1];
    u16x8 o;
#pragma unroll
    for (int t = 0; t < 4; ++t) { o[t] = f2bf(a[t]); o[4 + t] = f2bf(b[t]); }
    ((u16x8*)xb)[i] = o;
  } else if (i < nx8 + nw8) {
    const long long j = i - nx8;
    f32x4 a  = ((const f32x4*)w)[2 * j];
    f32x4 b  = ((const f32x4*)w)[2 * j + 1];
    f32x4 ma = ((const f32x4*)msk)[2 * j];
    f32x4 mb = ((const f32x4*)msk)[2 * j + 1];
    u16x8 o;
#pragma unroll
    for (int t = 0; t < 4; ++t) {
      o[t]     = f2bf(a[t] * ma[t]);
      o[4 + t] = f2bf(b[t] * mb[t]);
    }
    ((u16x8*)wb)[j] = o;
  }
}

// Pass 2: C = Xb * Wb^T, m97-style: 128x128 tile, BK=64, 4 waves, 4x4 16x16x32
// MFMA fragments per wave. PRE=true reads pre-converted bf16 via global_load_lds;
// PRE=false (ws too small fallback) loads fp32, converts in registers, ds_writes.
template <bool PRE>
__global__ __launch_bounds__(256) void gemm_kernel(
    const unsigned short* __restrict__ Ab, const unsigned short* __restrict__ Bb,
    const float* __restrict__ Af, const float* __restrict__ Wf,
    const float* __restrict__ Mf, float* __restrict__ C) {
  __shared__ __align__(16) unsigned short lA[128 * 64];  // [row][k], 16B-chunk XOR swizzled
  __shared__ __align__(16) unsigned short lB[128 * 64];

  const int tid = threadIdx.x;
  const int nt = blockIdx.x & 7;    // N/128 = 8 tiles (fast dim: A-panel L2 reuse)
  const int mt = blockIdx.x >> 3;   // M/128 = 256 tiles
  const int m0 = mt * 128, n0 = nt * 128;
  const int lane = tid & 63;
  const int wv = tid >> 6;
  const int q = lane >> 4, r = lane & 15;
  const int wm = (wv >> 1) * 64, wn = (wv & 1) * 64;

  f32x4 acc[4][4] = {};

  // staging coords: linear chunk p -> (row, stored-chunk cs); fetch global chunk
  // cg = cs ^ (row&7) so fragment reads are conflict-free.
  int prow[4], pcg[4];
#pragma unroll
  for (int i = 0; i < 4; ++i) {
    const int p = i * 256 + tid;
    prow[i] = p >> 3;
    pcg[i] = (p & 7) ^ (prow[i] & 7);
  }

  for (int kt = 0; kt < KDIM / 64; ++kt) {
    const int k0 = kt * 64;
    if (PRE) {
#pragma unroll
      for (int i = 0; i < 4; ++i) {
        const int p = i * 256 + tid;
        async16(Ab + (size_t)(m0 + prow[i]) * KDIM + k0 + pcg[i] * 8, &lA[p * 8]);
        async16(Bb + (size_t)(n0 + prow[i]) * KDIM + k0 + pcg[i] * 8, &lB[p * 8]);
      }
    } else {
#pragma unroll
      for (int i = 0; i < 4; ++i) {
        const int p = i * 256 + tid;
        const size_t offA = (size_t)(m0 + prow[i]) * KDIM + k0 + pcg[i] * 8;
        const size_t offB = (size_t)(n0 + prow[i]) * KDIM + k0 + pcg[i] * 8;
        f32x4 a0 = *(const f32x4*)(Af + offA);
        f32x4 a1 = *(const f32x4*)(Af + offA + 4);
        f32x4 w0 = *(const f32x4*)(Wf + offB);
        f32x4 w1 = *(const f32x4*)(Wf + offB + 4);
        f32x4 k0v = *(const f32x4*)(Mf + offB);
        f32x4 k1v = *(const f32x4*)(Mf + offB + 4);
        u16x8 oa, ob;
#pragma unroll
        for (int t = 0; t < 4; ++t) {
          oa[t] = f2bf(a0[t]); oa[4 + t] = f2bf(a1[t]);
          ob[t] = f2bf(w0[t] * k0v[t]); ob[4 + t] = f2bf(w1[t] * k1v[t]);
        }
        *(u16x8*)&lA[p * 8] = oa;
        *(u16x8*)&lB[p * 8] = ob;
      }
    }
    __syncthreads();  // drains vmcnt(0) for global_load_lds before LDS reads
#pragma unroll
    for (int kk = 0; kk < 2; ++kk) {
      s16x8 av[4], bv[4];
#pragma unroll
      for (int i = 0; i < 4; ++i) {
        const int ar = wm + 16 * i + r;
        av[i] = *(const s16x8*)&lA[ar * 64 + (((kk << 2) | q) ^ (ar & 7)) * 8];
        const int br = wn + 16 * i + r;
        bv[i] = *(const s16x8*)&lB[br * 64 + (((kk << 2) | q) ^ (br & 7)) * 8];
      }
#pragma unroll
      for (int i = 0; i < 4; ++i)
#pragma unroll
        for (int j = 0; j < 4; ++j)
          acc[i][j] = __builtin_amdgcn_mfma_f32_16x16x32_bf16(av[i], bv[j],
                                                              acc[i][j], 0, 0, 0);
    }
    __syncthreads();
  }

  // epilogue: C/D layout col=lane&15, row=(lane>>4)*4+reg (m89-verified)
#pragma unroll
  for (int i = 0; i < 4; ++i) {
    const int rowb = m0 + wm + 16 * i + q * 4;
#pragma unroll
    for (int j = 0; j < 4; ++j) {
      const int col = n0 + wn + 16 * j + r;
#pragma unroll
      for (int t = 0; t < 4; ++t)
        C[(size_t)(rowb + t) * NDIM + col] = acc[i][j][t];
    }
  }
}

extern "C" void kernel_launch(void* const* d_in, const int* in_sizes, int n_in,
                              void* d_out, int out_size, void* d_ws, size_t ws_size,
                              hipStream_t stream) {
  (void)in_sizes; (void)n_in; (void)out_size;
  const float* x  = (const float*)d_in[0];
  const float* w  = (const float*)d_in[1];
  const float* mk = (const float*)d_in[2];
  float* out = (float*)d_out;

  const size_t xb_bytes = (size_t)MDIM * KDIM * 2;  // 64 MiB
  const size_t wb_bytes = (size_t)NDIM * KDIM * 2;  // 2 MiB
  const int gemm_blocks = (MDIM / 128) * (NDIM / 128);  // 2048

  if (ws_size >= xb_bytes + wb_bytes) {
    unsigned short* xb = (unsigned short*)d_ws;
    unsigned short* wb = (unsigned short*)((char*)d_ws + xb_bytes);
    const long long tot8 = ((long long)MDIM * KDIM + (long long)NDIM * KDIM) / 8;
    const int cblocks = (int)((tot8 + 255) / 256);
    hipLaunchKernelGGL(convert_kernel, dim3(cblocks), dim3(256), 0, stream,
                       x, w, mk, xb, wb);
    hipLaunchKernelGGL((gemm_kernel<true>), dim3(gemm_blocks), dim3(256), 0, stream,
                       xb, wb, nullptr, nullptr, nullptr, out);
  } else {
    hipLaunchKernelGGL((gemm_kernel<false>), dim3(gemm_blocks), dim3(256), 0, stream,
                       nullptr, nullptr, x, w, mk, out);
  }
}

// Round 2
// 310.239 us; speedup vs baseline: 1.0478x; 1.0478x over previous
//
#include <hip/hip_runtime.h>
#include <hip/hip_bf16.h>
#include <cstdint>

#define MDIM 32768
#define NDIM 1024
#define KDIM 1024

typedef float          f32x4 __attribute__((ext_vector_type(4)));
typedef short          s16x8 __attribute__((ext_vector_type(8)));
typedef unsigned short u16x4 __attribute__((ext_vector_type(4)));
typedef unsigned short u16x8 __attribute__((ext_vector_type(8)));

typedef __attribute__((address_space(1))) unsigned int gu32;
typedef __attribute__((address_space(3))) unsigned int lu32;

// fp32 -> bf16 round-to-nearest-even (inputs are finite; no NaN handling needed)
__device__ __forceinline__ unsigned short f2bf(float f) {
  unsigned int u = __builtin_bit_cast(unsigned int, f);
  u += 0x7fffu + ((u >> 16) & 1u);
  return (unsigned short)(u >> 16);
}

// async global->LDS, 16 bytes per lane (global_load_lds_dwordx4).
// LDS dest is wave-uniform base + lane*16; callers pass lane-linear addresses.
__device__ __forceinline__ void async16(const void* g, void* l) {
  __builtin_amdgcn_global_load_lds((gu32*)g, (lu32*)l, 16, 0, 0);
}

// Pass 1: x (fp32 [M,K]) -> bf16, and (w*mask) (fp32 [N,K]) -> bf16.
// One f32x4 load + one u16x4 store per thread: every instruction fully
// coalesced across the wave (16B/lane read, 8B/lane write).
__global__ __launch_bounds__(256) void convert_kernel(
    const float* __restrict__ x, const float* __restrict__ w,
    const float* __restrict__ msk,
    unsigned short* __restrict__ xb, unsigned short* __restrict__ wb) {
  const long long i = (long long)blockIdx.x * 256 + threadIdx.x;  // 4-elem group
  const long long nx4 = (long long)MDIM * KDIM / 4;
  const long long nw4 = (long long)NDIM * KDIM / 4;
  if (i < nx4) {
    f32x4 a = ((const f32x4*)x)[i];
    u16x4 o;
#pragma unroll
    for (int t = 0; t < 4; ++t) o[t] = f2bf(a[t]);
    ((u16x4*)xb)[i] = o;
  } else if (i < nx4 + nw4) {
    const long long j = i - nx4;
    f32x4 a = ((const f32x4*)w)[j];
    f32x4 m = ((const f32x4*)msk)[j];
    u16x4 o;
#pragma unroll
    for (int t = 0; t < 4; ++t) o[t] = f2bf(a[t] * m[t]);
    ((u16x4*)wb)[j] = o;
  }
}

// Pass 2: C = Xb * Wb^T, m97-style: 128x128 tile, BK=64, 4 waves, 4x4 16x16x32
// MFMA fragments per wave. PRE=true reads pre-converted bf16 via global_load_lds;
// PRE=false (ws too small fallback) loads fp32, converts in registers, ds_writes.
template <bool PRE>
__global__ __launch_bounds__(256) void gemm_kernel(
    const unsigned short* __restrict__ Ab, const unsigned short* __restrict__ Bb,
    const float* __restrict__ Af, const float* __restrict__ Wf,
    const float* __restrict__ Mf, float* __restrict__ C) {
  __shared__ __align__(16) unsigned short lA[128 * 64];  // [row][k], 16B-chunk XOR swizzled
  __shared__ __align__(16) unsigned short lB[128 * 64];

  const int tid = threadIdx.x;
  // XCD-aware swizzle: blocks round-robin across 8 XCDs by blockIdx%8.
  // Give XCD k the contiguous mt range [32k, 32k+32); within an XCD the 8
  // nt-sharers of one A-panel are consecutive -> co-resident -> panel stripe
  // (~320 KB) + whole Wb (2 MB) stay in that XCD's 4 MB L2.
  const int g = blockIdx.x;          // 2048 blocks
  const int xcd = g & 7;
  const int local = g >> 3;          // 0..255 within XCD
  const int nt = local & 7;          // N/128 = 8 tiles
  const int mt = xcd * 32 + (local >> 3);  // M/128 = 256 tiles
  const int m0 = mt * 128, n0 = nt * 128;
  const int lane = tid & 63;
  const int wv = tid >> 6;
  const int q = lane >> 4, r = lane & 15;
  const int wm = (wv >> 1) * 64, wn = (wv & 1) * 64;

  f32x4 acc[4][4] = {};

  // staging coords: linear chunk p -> (row, stored-chunk cs); fetch global chunk
  // cg = cs ^ (row&7) so fragment reads are conflict-free.
  int prow[4], pcg[4];
#pragma unroll
  for (int i = 0; i < 4; ++i) {
    const int p = i * 256 + tid;
    prow[i] = p >> 3;
    pcg[i] = (p & 7) ^ (prow[i] & 7);
  }

  for (int kt = 0; kt < KDIM / 64; ++kt) {
    const int k0 = kt * 64;
    if (PRE) {
#pragma unroll
      for (int i = 0; i < 4; ++i) {
        const int p = i * 256 + tid;
        async16(Ab + (size_t)(m0 + prow[i]) * KDIM + k0 + pcg[i] * 8, &lA[p * 8]);
        async16(Bb + (size_t)(n0 + prow[i]) * KDIM + k0 + pcg[i] * 8, &lB[p * 8]);
      }
    } else {
#pragma unroll
      for (int i = 0; i < 4; ++i) {
        const int p = i * 256 + tid;
        const size_t offA = (size_t)(m0 + prow[i]) * KDIM + k0 + pcg[i] * 8;
        const size_t offB = (size_t)(n0 + prow[i]) * KDIM + k0 + pcg[i] * 8;
        f32x4 a0 = *(const f32x4*)(Af + offA);
        f32x4 a1 = *(const f32x4*)(Af + offA + 4);
        f32x4 w0 = *(const f32x4*)(Wf + offB);
        f32x4 w1 = *(const f32x4*)(Wf + offB + 4);
        f32x4 k0v = *(const f32x4*)(Mf + offB);
        f32x4 k1v = *(const f32x4*)(Mf + offB + 4);
        u16x8 oa, ob;
#pragma unroll
        for (int t = 0; t < 4; ++t) {
          oa[t] = f2bf(a0[t]); oa[4 + t] = f2bf(a1[t]);
          ob[t] = f2bf(w0[t] * k0v[t]); ob[4 + t] = f2bf(w1[t] * k1v[t]);
        }
        *(u16x8*)&lA[p * 8] = oa;
        *(u16x8*)&lB[p * 8] = ob;
      }
    }
    __syncthreads();  // drains vmcnt(0) for global_load_lds before LDS reads
#pragma unroll
    for (int kk = 0; kk < 2; ++kk) {
      s16x8 av[4], bv[4];
#pragma unroll
      for (int i = 0; i < 4; ++i) {
        const int ar = wm + 16 * i + r;
        av[i] = *(const s16x8*)&lA[ar * 64 + (((kk << 2) | q) ^ (ar & 7)) * 8];
        const int br = wn + 16 * i + r;
        bv[i] = *(const s16x8*)&lB[br * 64 + (((kk << 2) | q) ^ (br & 7)) * 8];
      }
#pragma unroll
      for (int i = 0; i < 4; ++i)
#pragma unroll
        for (int j = 0; j < 4; ++j)
          acc[i][j] = __builtin_amdgcn_mfma_f32_16x16x32_bf16(av[i], bv[j],
                                                              acc[i][j], 0, 0, 0);
    }
    __syncthreads();
  }

  // epilogue: C/D layout col=lane&15, row=(lane>>4)*4+reg (m89-verified)
#pragma unroll
  for (int i = 0; i < 4; ++i) {
    const int rowb = m0 + wm + 16 * i + q * 4;
#pragma unroll
    for (int j = 0; j < 4; ++j) {
      const int col = n0 + wn + 16 * j + r;
#pragma unroll
      for (int t = 0; t < 4; ++t)
        C[(size_t)(rowb + t) * NDIM + col] = acc[i][j][t];
    }
  }
}

extern "C" void kernel_launch(void* const* d_in, const int* in_sizes, int n_in,
                              void* d_out, int out_size, void* d_ws, size_t ws_size,
                              hipStream_t stream) {
  (void)in_sizes; (void)n_in; (void)out_size;
  const float* x  = (const float*)d_in[0];
  const float* w  = (const float*)d_in[1];
  const float* mk = (const float*)d_in[2];
  float* out = (float*)d_out;

  const size_t xb_bytes = (size_t)MDIM * KDIM * 2;  // 64 MiB
  const size_t wb_bytes = (size_t)NDIM * KDIM * 2;  // 2 MiB
  const int gemm_blocks = (MDIM / 128) * (NDIM / 128);  // 2048

  if (ws_size >= xb_bytes + wb_bytes) {
    unsigned short* xb = (unsigned short*)d_ws;
    unsigned short* wb = (unsigned short*)((char*)d_ws + xb_bytes);
    const long long tot4 = ((long long)MDIM * KDIM + (long long)NDIM * KDIM) / 4;
    const int cblocks = (int)((tot4 + 255) / 256);
    hipLaunchKernelGGL(convert_kernel, dim3(cblocks), dim3(256), 0, stream,
                       x, w, mk, xb, wb);
    hipLaunchKernelGGL((gemm_kernel<true>), dim3(gemm_blocks), dim3(256), 0, stream,
                       xb, wb, nullptr, nullptr, nullptr, out);
  } else {
    hipLaunchKernelGGL((gemm_kernel<false>), dim3(gemm_blocks), dim3(256), 0, stream,
                       nullptr, nullptr, x, w, mk, out);
  }
}

// Round 3
// 273.534 us; speedup vs baseline: 1.1884x; 1.1342x over previous
//
#include <hip/hip_runtime.h>
#include <hip/hip_bf16.h>
#include <cstdint>

#define MDIM 32768
#define NDIM 1024
#define KDIM 1024
#define KC   512   // compacted K (2:4 structured mask -> 2 of every 4 cols active)

typedef float          f32x4 __attribute__((ext_vector_type(4)));
typedef int            i32x4 __attribute__((ext_vector_type(4)));
typedef short          s16x8 __attribute__((ext_vector_type(8)));
typedef unsigned short u16x4 __attribute__((ext_vector_type(4)));
typedef unsigned short u16x8 __attribute__((ext_vector_type(8)));

typedef __attribute__((address_space(1))) unsigned int gu32;
typedef __attribute__((address_space(3))) unsigned int lu32;

// fp32 -> bf16 round-to-nearest-even (inputs are finite; no NaN handling needed)
__device__ __forceinline__ unsigned short f2bf(float f) {
  unsigned int u = __builtin_bit_cast(unsigned int, f);
  u += 0x7fffu + ((u >> 16) & 1u);
  return (unsigned short)(u >> 16);
}

// select v[i], i in [0,4) — explicit cndmask tree (avoids scratch spill from
// dynamic ext_vector indexing)
__device__ __forceinline__ float pick4(f32x4 v, int i) {
  float lo = (i & 1) ? v[1] : v[0];
  float hi = (i & 1) ? v[3] : v[2];
  return (i & 2) ? hi : lo;
}

// async global->LDS, 16 bytes per lane (global_load_lds_dwordx4).
// LDS dest is wave-uniform base + lane*16; callers pass lane-linear addresses.
__device__ __forceinline__ void async16(const void* g, void* l) {
  __builtin_amdgcn_global_load_lds((gu32*)g, (lu32*)l, 16, 0, 0);
}

// Pass 0: build colmap[KC] = sorted global indices of active columns.
// mask pattern is identical for all rows (2 of each group of 4, whole column).
__global__ __launch_bounds__(256) void colmap_kernel(
    const float* __restrict__ msk, int* __restrict__ cmap) {
  const int g = threadIdx.x;  // one group of 4 input cols; 256 groups
  const float m0 = msk[4 * g + 0], m1 = msk[4 * g + 1];
  const float m2 = msk[4 * g + 2], m3 = msk[4 * g + 3];
  int i0 = -1, i1 = -1;
#pragma unroll
  for (int t = 0; t < 4; ++t) {
    const float mv = (t == 0) ? m0 : (t == 1) ? m1 : (t == 2) ? m2 : m3;
    if (mv != 0.0f) { if (i0 < 0) i0 = 4 * g + t; else i1 = 4 * g + t; }
  }
  cmap[2 * g + 0] = i0;
  cmap[2 * g + 1] = i1;
}

// Pass 1: compact+convert. Each thread: one 8-col input window (2 groups of 4)
// -> 4 compacted bf16 outputs. 32 B coalesced read, 8 B coalesced write.
// Masked-out columns are dropped entirely (their W entries are exactly 0.0,
// so the compacted GEMM is numerically identical up to fp32-accum order).
__global__ __launch_bounds__(256) void compact_kernel(
    const float* __restrict__ x, const float* __restrict__ w,
    const int* __restrict__ cmap,
    unsigned short* __restrict__ xb, unsigned short* __restrict__ wb) {
  const long long i = (long long)blockIdx.x * 256 + threadIdx.x;
  const long long nxw = (long long)MDIM * KDIM / 8;  // x windows
  const long long nww = (long long)NDIM * KDIM / 8;  // w windows
  const float* src;
  unsigned short* dst;
  long long j;
  if (i < nxw) { src = x; dst = xb; j = i; }
  else if (i < nxw + nww) { src = w; dst = wb; j = i - nxw; }
  else return;

  const int wi = (int)(j & 127);            // window within row (K/8 = 128)
  const long long row = j >> 7;
  const float* p = src + row * KDIM + wi * 8;
  f32x4 a = *(const f32x4*)p;
  f32x4 b = *(const f32x4*)(p + 4);
  i32x4 cm = ((const i32x4*)cmap)[wi];      // 4 active cols of this window
  const int base = wi * 8;
  u16x4 o;
  o[0] = f2bf(pick4(a, cm[0] - base));
  o[1] = f2bf(pick4(a, cm[1] - base));
  o[2] = f2bf(pick4(b, cm[2] - base - 4));
  o[3] = f2bf(pick4(b, cm[3] - base - 4));
  ((u16x4*)dst)[j] = o;
}

// Pass 2: C = Xb * Wb^T over compacted K. m97-style: 128x128 tile, BK=64,
// 4 waves, 4x4 16x16x32 MFMA fragments per wave. PRE=true reads compacted
// bf16 (K=512) via global_load_lds; PRE=false is the ws-too-small fallback:
// full K=1024 fp32 loads, convert in regs, ds_write.
template <bool PRE>
__global__ __launch_bounds__(256) void gemm_kernel(
    const unsigned short* __restrict__ Ab, const unsigned short* __restrict__ Bb,
    const float* __restrict__ Af, const float* __restrict__ Wf,
    const float* __restrict__ Mf, float* __restrict__ C) {
  __shared__ __align__(16) unsigned short lA[128 * 64];  // [row][k], 16B-chunk XOR swizzled
  __shared__ __align__(16) unsigned short lB[128 * 64];

  constexpr int kstr = PRE ? KC : KDIM;   // row stride in elements
  constexpr int kiters = kstr / 64;

  const int tid = threadIdx.x;
  // XCD-aware swizzle: blocks round-robin across 8 XCDs by blockIdx%8.
  // XCD k owns contiguous mt range; the 8 nt-sharers of one A-panel are
  // consecutive within an XCD -> panel stripe + whole Wb stay in its 4MB L2.
  const int g = blockIdx.x;          // 2048 blocks
  const int xcd = g & 7;
  const int local = g >> 3;          // 0..255 within XCD
  const int nt = local & 7;          // N/128 = 8 tiles
  const int mt = xcd * 32 + (local >> 3);  // M/128 = 256 tiles
  const int m0 = mt * 128, n0 = nt * 128;
  const int lane = tid & 63;
  const int wv = tid >> 6;
  const int q = lane >> 4, r = lane & 15;
  const int wm = (wv >> 1) * 64, wn = (wv & 1) * 64;

  f32x4 acc[4][4] = {};

  // staging coords: linear chunk p -> (row, stored-chunk cs); fetch global chunk
  // cg = cs ^ (row&7) so fragment reads are conflict-free.
  int prow[4], pcg[4];
#pragma unroll
  for (int i = 0; i < 4; ++i) {
    const int p = i * 256 + tid;
    prow[i] = p >> 3;
    pcg[i] = (p & 7) ^ (prow[i] & 7);
  }

  for (int kt = 0; kt < kiters; ++kt) {
    const int k0 = kt * 64;
    if (PRE) {
#pragma unroll
      for (int i = 0; i < 4; ++i) {
        const int p = i * 256 + tid;
        async16(Ab + (size_t)(m0 + prow[i]) * kstr + k0 + pcg[i] * 8, &lA[p * 8]);
        async16(Bb + (size_t)(n0 + prow[i]) * kstr + k0 + pcg[i] * 8, &lB[p * 8]);
      }
    } else {
#pragma unroll
      for (int i = 0; i < 4; ++i) {
        const int p = i * 256 + tid;
        const size_t offA = (size_t)(m0 + prow[i]) * kstr + k0 + pcg[i] * 8;
        const size_t offB = (size_t)(n0 + prow[i]) * kstr + k0 + pcg[i] * 8;
        f32x4 a0 = *(const f32x4*)(Af + offA);
        f32x4 a1 = *(const f32x4*)(Af + offA + 4);
        f32x4 w0 = *(const f32x4*)(Wf + offB);
        f32x4 w1 = *(const f32x4*)(Wf + offB + 4);
        f32x4 k0v = *(const f32x4*)(Mf + offB);
        f32x4 k1v = *(const f32x4*)(Mf + offB + 4);
        u16x8 oa, ob;
#pragma unroll
        for (int t = 0; t < 4; ++t) {
          oa[t] = f2bf(a0[t]); oa[4 + t] = f2bf(a1[t]);
          ob[t] = f2bf(w0[t] * k0v[t]); ob[4 + t] = f2bf(w1[t] * k1v[t]);
        }
        *(u16x8*)&lA[p * 8] = oa;
        *(u16x8*)&lB[p * 8] = ob;
      }
    }
    __syncthreads();  // drains vmcnt(0) for global_load_lds before LDS reads
#pragma unroll
    for (int kk = 0; kk < 2; ++kk) {
      s16x8 av[4], bv[4];
#pragma unroll
      for (int i = 0; i < 4; ++i) {
        const int ar = wm + 16 * i + r;
        av[i] = *(const s16x8*)&lA[ar * 64 + (((kk << 2) | q) ^ (ar & 7)) * 8];
        const int br = wn + 16 * i + r;
        bv[i] = *(const s16x8*)&lB[br * 64 + (((kk << 2) | q) ^ (br & 7)) * 8];
      }
#pragma unroll
      for (int i = 0; i < 4; ++i)
#pragma unroll
        for (int j = 0; j < 4; ++j)
          acc[i][j] = __builtin_amdgcn_mfma_f32_16x16x32_bf16(av[i], bv[j],
                                                              acc[i][j], 0, 0, 0);
    }
    __syncthreads();
  }

  // epilogue: C/D layout col=lane&15, row=(lane>>4)*4+reg (m89-verified)
#pragma unroll
  for (int i = 0; i < 4; ++i) {
    const int rowb = m0 + wm + 16 * i + q * 4;
#pragma unroll
    for (int j = 0; j < 4; ++j) {
      const int col = n0 + wn + 16 * j + r;
#pragma unroll
      for (int t = 0; t < 4; ++t)
        C[(size_t)(rowb + t) * NDIM + col] = acc[i][j][t];
    }
  }
}

extern "C" void kernel_launch(void* const* d_in, const int* in_sizes, int n_in,
                              void* d_out, int out_size, void* d_ws, size_t ws_size,
                              hipStream_t stream) {
  (void)in_sizes; (void)n_in; (void)out_size;
  const float* x  = (const float*)d_in[0];
  const float* w  = (const float*)d_in[1];
  const float* mk = (const float*)d_in[2];
  float* out = (float*)d_out;

  const size_t xb_bytes = (size_t)MDIM * KC * 2;  // 32 MiB
  const size_t wb_bytes = (size_t)NDIM * KC * 2;  // 1 MiB
  const size_t cm_bytes = KC * sizeof(int);       // 2 KiB
  const int gemm_blocks = (MDIM / 128) * (NDIM / 128);  // 2048

  if (ws_size >= xb_bytes + wb_bytes + cm_bytes) {
    unsigned short* xb = (unsigned short*)d_ws;
    unsigned short* wb = (unsigned short*)((char*)d_ws + xb_bytes);
    int* cmap = (int*)((char*)d_ws + xb_bytes + wb_bytes);
    hipLaunchKernelGGL(colmap_kernel, dim3(1), dim3(256), 0, stream, mk, cmap);
    const long long totw = ((long long)MDIM * KDIM + (long long)NDIM * KDIM) / 8;
    const int cblocks = (int)((totw + 255) / 256);
    hipLaunchKernelGGL(compact_kernel, dim3(cblocks), dim3(256), 0, stream,
                       x, w, cmap, xb, wb);
    hipLaunchKernelGGL((gemm_kernel<true>), dim3(gemm_blocks), dim3(256), 0, stream,
                       xb, wb, nullptr, nullptr, nullptr, out);
  } else {
    hipLaunchKernelGGL((gemm_kernel<false>), dim3(gemm_blocks), dim3(256), 0, stream,
                       nullptr, nullptr, x, w, mk, out);
  }
}

// Round 4
// 272.053 us; speedup vs baseline: 1.1949x; 1.0054x over previous
//
#include <hip/hip_runtime.h>
#include <hip/hip_bf16.h>
#include <cstdint>

#define MDIM 32768
#define NDIM 1024
#define KDIM 1024
#define KC   512   // compacted K (2:4 structured mask -> 2 of every 4 cols active)

typedef float          f32x4 __attribute__((ext_vector_type(4)));
typedef short          s16x8 __attribute__((ext_vector_type(8)));
typedef unsigned short u16x4 __attribute__((ext_vector_type(4)));
typedef unsigned short u16x8 __attribute__((ext_vector_type(8)));

typedef __attribute__((address_space(1))) unsigned int gu32;
typedef __attribute__((address_space(3))) unsigned int lu32;

// fp32 -> bf16 round-to-nearest-even (inputs are finite; no NaN handling needed)
__device__ __forceinline__ unsigned short f2bf(float f) {
  unsigned int u = __builtin_bit_cast(unsigned int, f);
  u += 0x7fffu + ((u >> 16) & 1u);
  return (unsigned short)(u >> 16);
}

// Branchless 2-of-4 column selection from mask values (exactly 2 of m0..m3 are
// nonzero). Covers all six patterns:
//   first active:  m0 ? v0 : (m1 ? v1 : v2)
//   second active: m3 ? v3 : (m2 ? v2 : v1)
__device__ __forceinline__ float sel_first(f32x4 v, f32x4 m) {
  return m[0] != 0.0f ? v[0] : (m[1] != 0.0f ? v[1] : v[2]);
}
__device__ __forceinline__ float sel_second(f32x4 v, f32x4 m) {
  return m[3] != 0.0f ? v[3] : (m[2] != 0.0f ? v[2] : v[1]);
}

// async global->LDS, 16 bytes per lane (global_load_lds_dwordx4).
// LDS dest is wave-uniform base + lane*16; callers pass lane-linear addresses.
__device__ __forceinline__ void async16(const void* g, void* l) {
  __builtin_amdgcn_global_load_lds((gu32*)g, (lu32*)l, 16, 0, 0);
}

// Pass 1: fused compact+convert (colmap kernel eliminated — selection derived
// in-thread from mask values; the 2:4 pattern is column-uniform so row 0's
// pattern orders the compacted K identically for X and W).
// Each thread: one 8-col window -> 4 compacted bf16. 32 B coalesced read,
// 8 B coalesced write; mask reads are L1-hot (row 0 shared block-wide).
__global__ __launch_bounds__(256) void compact_kernel(
    const float* __restrict__ x, const float* __restrict__ w,
    const float* __restrict__ msk,
    unsigned short* __restrict__ xb, unsigned short* __restrict__ wb) {
  const long long i = (long long)blockIdx.x * 256 + threadIdx.x;
  const long long nxw = (long long)MDIM * KDIM / 8;  // x windows
  const long long nww = (long long)NDIM * KDIM / 8;  // w windows
  if (i < nxw) {
    const int wi = (int)(i & 127);
    const long long row = i >> 7;
    const float* p = x + row * KDIM + wi * 8;
    f32x4 a = *(const f32x4*)p;
    f32x4 b = *(const f32x4*)(p + 4);
    f32x4 ma = *(const f32x4*)(msk + wi * 8);      // row-0 pattern
    f32x4 mb = *(const f32x4*)(msk + wi * 8 + 4);
    u16x4 o;
    o[0] = f2bf(sel_first(a, ma));
    o[1] = f2bf(sel_second(a, ma));
    o[2] = f2bf(sel_first(b, mb));
    o[3] = f2bf(sel_second(b, mb));
    ((u16x4*)xb)[i] = o;
  } else if (i < nxw + nww) {
    const long long j = i - nxw;
    const int wi = (int)(j & 127);
    const long long row = j >> 7;
    const float* p = w + row * KDIM + wi * 8;
    f32x4 a = *(const f32x4*)p;
    f32x4 b = *(const f32x4*)(p + 4);
    f32x4 moa = *(const f32x4*)(msk + row * KDIM + wi * 8);  // own-row mask
    f32x4 mob = *(const f32x4*)(msk + row * KDIM + wi * 8 + 4);
    f32x4 ma = *(const f32x4*)(msk + wi * 8);                // row-0 pattern
    f32x4 mb = *(const f32x4*)(msk + wi * 8 + 4);
#pragma unroll
    for (int t = 0; t < 4; ++t) { a[t] *= moa[t]; b[t] *= mob[t]; }  // faithful w*mask
    u16x4 o;
    o[0] = f2bf(sel_first(a, ma));
    o[1] = f2bf(sel_second(a, ma));
    o[2] = f2bf(sel_first(b, mb));
    o[3] = f2bf(sel_second(b, mb));
    ((u16x4*)wb)[j] = o;
  }
}

// Pass 2: C = Xb * Wb^T over compacted K. m97-style: 128x128 tile, BK=64,
// 4 waves, 4x4 16x16x32 MFMA fragments per wave. Operands SWAPPED
// (mfma(bv, av)) so the C/D fragment is transposed: reg t walks 4 consecutive
// N-columns -> epilogue is 16 aligned f32x4 stores/thread (was 64 dwords).
// PRE=true reads compacted bf16 (K=512) via global_load_lds; PRE=false is the
// ws-too-small fallback: full K=1024 fp32 loads, convert in regs, ds_write.
template <bool PRE>
__global__ __launch_bounds__(256) void gemm_kernel(
    const unsigned short* __restrict__ Ab, const unsigned short* __restrict__ Bb,
    const float* __restrict__ Af, const float* __restrict__ Wf,
    const float* __restrict__ Mf, float* __restrict__ C) {
  __shared__ __align__(16) unsigned short lA[128 * 64];  // [row][k], 16B-chunk XOR swizzled
  __shared__ __align__(16) unsigned short lB[128 * 64];

  constexpr int kstr = PRE ? KC : KDIM;   // row stride in elements
  constexpr int kiters = kstr / 64;

  const int tid = threadIdx.x;
  // XCD-aware swizzle: blocks round-robin across 8 XCDs by blockIdx%8.
  // XCD k owns contiguous mt range; the 8 nt-sharers of one A-panel are
  // consecutive within an XCD -> panel stripe + whole Wb stay in its 4MB L2.
  const int g = blockIdx.x;          // 2048 blocks
  const int xcd = g & 7;
  const int local = g >> 3;          // 0..255 within XCD
  const int nt = local & 7;          // N/128 = 8 tiles
  const int mt = xcd * 32 + (local >> 3);  // M/128 = 256 tiles
  const int m0 = mt * 128, n0 = nt * 128;
  const int lane = tid & 63;
  const int wv = tid >> 6;
  const int q = lane >> 4, r = lane & 15;
  const int wm = (wv >> 1) * 64, wn = (wv & 1) * 64;

  f32x4 acc[4][4] = {};

  // staging coords: linear chunk p -> (row, stored-chunk cs); fetch global chunk
  // cg = cs ^ (row&7) so fragment reads are conflict-free.
  int prow[4], pcg[4];
#pragma unroll
  for (int i = 0; i < 4; ++i) {
    const int p = i * 256 + tid;
    prow[i] = p >> 3;
    pcg[i] = (p & 7) ^ (prow[i] & 7);
  }

  for (int kt = 0; kt < kiters; ++kt) {
    const int k0 = kt * 64;
    if (PRE) {
#pragma unroll
      for (int i = 0; i < 4; ++i) {
        const int p = i * 256 + tid;
        async16(Ab + (size_t)(m0 + prow[i]) * kstr + k0 + pcg[i] * 8, &lA[p * 8]);
        async16(Bb + (size_t)(n0 + prow[i]) * kstr + k0 + pcg[i] * 8, &lB[p * 8]);
      }
    } else {
#pragma unroll
      for (int i = 0; i < 4; ++i) {
        const int p = i * 256 + tid;
        const size_t offA = (size_t)(m0 + prow[i]) * kstr + k0 + pcg[i] * 8;
        const size_t offB = (size_t)(n0 + prow[i]) * kstr + k0 + pcg[i] * 8;
        f32x4 a0 = *(const f32x4*)(Af + offA);
        f32x4 a1 = *(const f32x4*)(Af + offA + 4);
        f32x4 w0 = *(const f32x4*)(Wf + offB);
        f32x4 w1 = *(const f32x4*)(Wf + offB + 4);
        f32x4 k0v = *(const f32x4*)(Mf + offB);
        f32x4 k1v = *(const f32x4*)(Mf + offB + 4);
        u16x8 oa, ob;
#pragma unroll
        for (int t = 0; t < 4; ++t) {
          oa[t] = f2bf(a0[t]); oa[4 + t] = f2bf(a1[t]);
          ob[t] = f2bf(w0[t] * k0v[t]); ob[4 + t] = f2bf(w1[t] * k1v[t]);
        }
        *(u16x8*)&lA[p * 8] = oa;
        *(u16x8*)&lB[p * 8] = ob;
      }
    }
    __syncthreads();  // drains vmcnt(0) for global_load_lds before LDS reads
#pragma unroll
    for (int kk = 0; kk < 2; ++kk) {
      s16x8 av[4], bv[4];
#pragma unroll
      for (int i = 0; i < 4; ++i) {
        const int ar = wm + 16 * i + r;
        av[i] = *(const s16x8*)&lA[ar * 64 + (((kk << 2) | q) ^ (ar & 7)) * 8];
        const int br = wn + 16 * i + r;
        bv[i] = *(const s16x8*)&lB[br * 64 + (((kk << 2) | q) ^ (br & 7)) * 8];
      }
#pragma unroll
      for (int i = 0; i < 4; ++i)
#pragma unroll
        for (int j = 0; j < 4; ++j)
          acc[i][j] = __builtin_amdgcn_mfma_f32_16x16x32_bf16(bv[j], av[i],
                                                              acc[i][j], 0, 0, 0);
    }
    __syncthreads();
  }

  // epilogue (transposed fragment): acc[i][j][t] = C[m0+wm+16i+r][n0+wn+16j+4q+t]
  // -> one aligned f32x4 store per (i,j).
#pragma unroll
  for (int i = 0; i < 4; ++i) {
    const size_t rowoff = (size_t)(m0 + wm + 16 * i + r) * NDIM;
#pragma unroll
    for (int j = 0; j < 4; ++j) {
      const int col = n0 + wn + 16 * j + 4 * q;
      *(f32x4*)&C[rowoff + col] = acc[i][j];
    }
  }
}

extern "C" void kernel_launch(void* const* d_in, const int* in_sizes, int n_in,
                              void* d_out, int out_size, void* d_ws, size_t ws_size,
                              hipStream_t stream) {
  (void)in_sizes; (void)n_in; (void)out_size;
  const float* x  = (const float*)d_in[0];
  const float* w  = (const float*)d_in[1];
  const float* mk = (const float*)d_in[2];
  float* out = (float*)d_out;

  const size_t xb_bytes = (size_t)MDIM * KC * 2;  // 32 MiB
  const size_t wb_bytes = (size_t)NDIM * KC * 2;  // 1 MiB
  const int gemm_blocks = (MDIM / 128) * (NDIM / 128);  // 2048

  if (ws_size >= xb_bytes + wb_bytes) {
    unsigned short* xb = (unsigned short*)d_ws;
    unsigned short* wb = (unsigned short*)((char*)d_ws + xb_bytes);
    const long long totw = ((long long)MDIM * KDIM + (long long)NDIM * KDIM) / 8;
    const int cblocks = (int)((totw + 255) / 256);
    hipLaunchKernelGGL(compact_kernel, dim3(cblocks), dim3(256), 0, stream,
                       x, w, mk, xb, wb);
    hipLaunchKernelGGL((gemm_kernel<true>), dim3(gemm_blocks), dim3(256), 0, stream,
                       xb, wb, nullptr, nullptr, nullptr, out);
  } else {
    hipLaunchKernelGGL((gemm_kernel<false>), dim3(gemm_blocks), dim3(256), 0, stream,
                       nullptr, nullptr, x, w, mk, out);
  }
}